// Round 11
// baseline (147.045 us; speedup 1.0000x reference)
//
#include <hip/hip_runtime.h>
#include <hip/hip_bf16.h>

typedef float f32x4  __attribute__((ext_vector_type(4)));
typedef short bf16x8 __attribute__((ext_vector_type(8)));

__device__ __forceinline__ short bf16r(float x) {
    unsigned u = __builtin_bit_cast(unsigned, x);
    u += 0x7fffu + ((u >> 16) & 1u);
    return (short)(u >> 16);
}

// prepass: pack head/dep f32 -> bf16 in MFMA-fragment-major layout:
// p[b][rb][kc][r][e] = x[b][rb*16+r][kc*8+e]   (rb=row/16, kc=k/8)
// -> a wave's fragment load (16 rows x 8 k) is 1KB fully contiguous.
__global__ void pack_kernel(const float* __restrict__ head, const float* __restrict__ dep,
                            short* __restrict__ hp, short* __restrict__ dp) {
    const int per = 8 * 512 * 64;                 // threads per tensor
    int gid = blockIdx.x * blockDim.x + threadIdx.x;
    const float* src = (gid < per) ? head : dep;
    short* dst = (gid < per) ? hp : dp;
    int g = (gid < per) ? gid : gid - per;
    const int r  = g & 15;            // row % 16  (fastest -> write coalescing)
    const int j8 = (g >> 4) & 63;     // k / 8
    const int ib = (g >> 10) & 31;    // row / 16
    const int b  = g >> 15;
    const float* s = src + ((size_t)(b * 512 + ib * 16 + r)) * 512 + j8 * 8;
    f32x4 a = *(const f32x4*)s;
    f32x4 c = *(const f32x4*)(s + 4);
    bf16x8 v;
#pragma unroll
    for (int e = 0; e < 4; ++e) { v[e] = bf16r(a[e]); v[4 + e] = bf16r(c[e]); }
    *(bf16x8*)(dst + ((((size_t)(b * 32 + ib)) * 64 + j8) * 16 + r) * 8) = v;
}

// ---- main: 128x128 tile x 2 l-values, 4 waves (2m x 2n, wave 64x64).
// ZERO LDS, ZERO barriers: A/B fragments load global->VGPR from the packed
// fragment-major layout (1KB coalesced per load, L2-resident); U broadcast
// from global; 2-bank prefetch. R11 fix vs R10: ISSUE(t+2) moved to END of
// STEP(t) -- bank (t+2)&1 == t&1, so issuing before consumption overwrote
// the operands being consumed (the R10 correctness bug).
__global__ __launch_bounds__(256, 2)
void bla_gemm11(const short* __restrict__ hp,
                const short* __restrict__ dp,
                const float* __restrict__ U,
                float* __restrict__ out)
{
    constexpr int S = 512, L = 32, NT = 16;      // 16 K-steps of 32

    const int tid = threadIdx.x, lane = tid & 63, wid = tid >> 6;
    const int wm = wid >> 1, wn = wid & 1;       // 2m x 2n, wave tile 64x64

    // XCD swizzle: 2048 blocks -> 256/XCD = one b per XCD (hp[b]+dp[b]=512KB, L2-hot)
    const int swz = (blockIdx.x & 7) * ((int)gridDim.x >> 3) + (blockIdx.x >> 3);
    const int b = swz >> 8, rem = swz & 255;
    const int it = rem >> 6, ot = (rem >> 4) & 3, lp = rem & 15;
    const int i0 = it * 128, o0 = ot * 128, l0 = lp * 2;

    // packed fragment bases; frag m: +m*8192 elems; step t: +t*512 elems
    const short* abase = hp + (((size_t)(b * 32 + (i0 >> 4) + wm * 4)) * 64
                               + (lane >> 4)) * 128 + (lane & 15) * 8;
    const short* bbase = dp + (((size_t)(b * 32 + (o0 >> 4) + wn * 4)) * 64
                               + (lane >> 4)) * 128 + (lane & 15) * 8;
    // U: lane's 8-elem k-slice; 16-lane groups share an address (broadcast)
    const float* u0 = U + (size_t)l0 * 512 + ((lane >> 4) << 3);
    const float* u1 = u0 + 512;

    bf16x8 ra[2][4], rb[2][4];        // 2-deep prefetch banks (static parity idx)
    f32x4  ru[2][2][2];               // [parity][l][half]
    f32x4  acc0[4][4] = {}, acc1[4][4] = {};

#define ISSUE(t_) do {                                                          \
        const int p_ = (t_) & 1;                                                \
        _Pragma("unroll")                                                       \
        for (int m = 0; m < 4; ++m)                                             \
            ra[p_][m] = *(const bf16x8*)(abase + m * 8192 + (t_) * 512);        \
        _Pragma("unroll")                                                       \
        for (int n = 0; n < 4; ++n)                                             \
            rb[p_][n] = *(const bf16x8*)(bbase + n * 8192 + (t_) * 512);        \
        ru[p_][0][0] = *(const f32x4*)(u0 + (t_) * 32);                         \
        ru[p_][0][1] = *(const f32x4*)(u0 + (t_) * 32 + 4);                     \
        ru[p_][1][0] = *(const f32x4*)(u1 + (t_) * 32);                         \
        ru[p_][1][1] = *(const f32x4*)(u1 + (t_) * 32 + 4);                     \
    } while (0)

    // one K=32 step: scale-by-U per l, 16 MFMA per l; prefetch ISSUE at the
    // END (after last read of bank p_ -- correctness requirement, see above)
#define STEP(t_) do {                                                           \
        const int p_ = (t_) & 1;                                                \
        _Pragma("unroll")                                                       \
        for (int m = 0; m < 4; ++m) {                                           \
            bf16x8 av;                                                          \
            _Pragma("unroll")                                                   \
            for (int e = 0; e < 8; ++e) {                                       \
                float f = __builtin_bit_cast(float,                             \
                    (unsigned)((unsigned short)ra[p_][m][e]) << 16)             \
                    * ru[p_][0][e >> 2][e & 3];                                 \
                av[e] = __builtin_bit_cast(short, __float2bfloat16(f));         \
            }                                                                   \
            _Pragma("unroll")                                                   \
            for (int n = 0; n < 4; ++n)                                         \
                acc0[m][n] = __builtin_amdgcn_mfma_f32_16x16x32_bf16(           \
                    av, rb[p_][n], acc0[m][n], 0, 0, 0);                        \
        }                                                                       \
        _Pragma("unroll")                                                       \
        for (int m = 0; m < 4; ++m) {                                           \
            bf16x8 av;                                                          \
            _Pragma("unroll")                                                   \
            for (int e = 0; e < 8; ++e) {                                       \
                float f = __builtin_bit_cast(float,                             \
                    (unsigned)((unsigned short)ra[p_][m][e]) << 16)             \
                    * ru[p_][1][e >> 2][e & 3];                                 \
                av[e] = __builtin_bit_cast(short, __float2bfloat16(f));         \
            }                                                                   \
            _Pragma("unroll")                                                   \
            for (int n = 0; n < 4; ++n)                                         \
                acc1[m][n] = __builtin_amdgcn_mfma_f32_16x16x32_bf16(           \
                    av, rb[p_][n], acc1[m][n], 0, 0, 0);                        \
        }                                                                       \
        if ((t_) + 2 < NT) ISSUE((t_) + 2);                                     \
    } while (0)

    ISSUE(0);
    ISSUE(1);
#pragma unroll
    for (int t = 0; t < NT; ++t)
        STEP(t);

    // epilogue: C/D layout col=lane&15, row=(lane>>4)*4+r; 2 l-planes
#pragma unroll
    for (int li = 0; li < 2; ++li) {
        float* op = out + (size_t)(b * L + l0 + li) * S * S;
#pragma unroll
        for (int m = 0; m < 4; ++m) {
            const int row0 = i0 + wm * 64 + m * 16 + ((lane >> 4) << 2);
#pragma unroll
            for (int n = 0; n < 4; ++n) {
                const int col = o0 + wn * 64 + n * 16 + (lane & 15);
#pragma unroll
                for (int r = 0; r < 4; ++r)
                    op[(size_t)(row0 + r) * S + col] =
                        li ? acc1[m][n][r] : acc0[m][n][r];
            }
        }
    }

#undef ISSUE
#undef STEP
}

// ---------------- fallback (proven R1 kernel): used only if ws < 8MB ----------
__global__ __launch_bounds__(256, 2)
void bla_fb(const float* __restrict__ head, const float* __restrict__ dep,
            const float* __restrict__ U, float* __restrict__ out)
{
    constexpr int S = 512, D = 512, L = 32, BM = 128, BN = 128, BK = 64, NT = 8;
    __shared__ short Al[2][BM * BK];
    __shared__ short Bl[2][BN * BK];
    const int tid = threadIdx.x, lane = tid & 63, wid = tid >> 6;
    const int wm = wid >> 1, wn = wid & 1;
    const int swz = (blockIdx.x & 7) * ((int)gridDim.x >> 3) + (blockIdx.x >> 3);
    const int b = swz >> 9, rem = swz & 511;
    const int l = rem >> 4, it = (rem >> 2) & 3, ot = rem & 3;
    const int i0 = it * BM, o0 = ot * BN;
    const int srow = tid >> 3, scol = (tid & 7) * 8, swb = scol * 2;
    const float* hb = head + (size_t)(b * S + i0 + srow) * D + scol;
    const float* db = dep + (size_t)(b * S + o0 + srow) * D + scol;
    const float* ub = U + l * D + scol;
    f32x4 ra[4][2], rb[4][2], ru[2];
#define FSTAGE_LOAD(t) do { const int k0_ = (t) * BK;                              \
        ru[0] = *(const f32x4*)(ub + k0_); ru[1] = *(const f32x4*)(ub + k0_ + 4);  \
        _Pragma("unroll") for (int p_ = 0; p_ < 4; ++p_) {                         \
            ra[p_][0] = *(const f32x4*)(hb + k0_ + p_ * 32 * D);                   \
            ra[p_][1] = *(const f32x4*)(hb + k0_ + p_ * 32 * D + 4);               \
            rb[p_][0] = *(const f32x4*)(db + k0_ + p_ * 32 * D);                   \
            rb[p_][1] = *(const f32x4*)(db + k0_ + p_ * 32 * D + 4); } } while (0)
#define FSTAGE_WRITE(buf) do { _Pragma("unroll") for (int p_ = 0; p_ < 4; ++p_) {  \
            const int row_ = srow + p_ * 32; const int sb_ = swb ^ ((row_ & 7) << 4); \
            bf16x8 av_, bv_;                                                       \
            _Pragma("unroll") for (int q_ = 0; q_ < 2; ++q_)                       \
                _Pragma("unroll") for (int j_ = 0; j_ < 4; ++j_) {                 \
                    av_[q_ * 4 + j_] = bf16r(ra[p_][q_][j_] * ru[q_][j_]);         \
                    bv_[q_ * 4 + j_] = bf16r(rb[p_][q_][j_]); }                    \
            *(bf16x8*)&Al[buf][row_ * BK + (sb_ >> 1)] = av_;                      \
            *(bf16x8*)&Bl[buf][row_ * BK + (sb_ >> 1)] = bv_; } } while (0)
    f32x4 acc[4][4] = {};
    const int cbase = (lane >> 4) << 4, rsw = (lane & 7) << 4;
#define FCOMPUTE(buf) do { _Pragma("unroll") for (int ks_ = 0; ks_ < 2; ++ks_) {   \
            const int sb2_ = (ks_ * 64 + cbase) ^ rsw; bf16x8 af_[4], bfr_[4];     \
            _Pragma("unroll") for (int f_ = 0; f_ < 4; ++f_) {                     \
                af_[f_] = *(const bf16x8*)&Al[buf][(wm * 64 + f_ * 16 + (lane & 15)) * BK + (sb2_ >> 1)]; \
                bfr_[f_] = *(const bf16x8*)&Bl[buf][(wn * 64 + f_ * 16 + (lane & 15)) * BK + (sb2_ >> 1)]; } \
            _Pragma("unroll") for (int fm_ = 0; fm_ < 4; ++fm_)                    \
                _Pragma("unroll") for (int fn_ = 0; fn_ < 4; ++fn_)                \
                    acc[fm_][fn_] = __builtin_amdgcn_mfma_f32_16x16x32_bf16(       \
                        af_[fm_], bfr_[fn_], acc[fm_][fn_], 0, 0, 0); } } while (0)
    FSTAGE_LOAD(0); FSTAGE_WRITE(0); __syncthreads();
    int cur = 0;
#pragma unroll
    for (int t = 0; t < NT; ++t) {
        if (t + 1 < NT) FSTAGE_LOAD(t + 1);
        FCOMPUTE(cur);
        if (t + 1 < NT) FSTAGE_WRITE(cur ^ 1);
        __syncthreads();
        cur ^= 1;
    }
    float* op = out + (size_t)(b * L + l) * S * S;
#pragma unroll
    for (int fm = 0; fm < 4; ++fm) {
        const int row0 = i0 + wm * 64 + fm * 16 + ((lane >> 4) << 2);
#pragma unroll
        for (int fn = 0; fn < 4; ++fn) {
            const int col = o0 + wn * 64 + fn * 16 + (lane & 15);
#pragma unroll
            for (int r = 0; r < 4; ++r)
                op[(size_t)(row0 + r) * S + col] = acc[fm][fn][r];
        }
    }
#undef FSTAGE_LOAD
#undef FSTAGE_WRITE
#undef FCOMPUTE
}

extern "C" void kernel_launch(void* const* d_in, const int* in_sizes, int n_in,
                              void* d_out, int out_size, void* d_ws, size_t ws_size,
                              hipStream_t stream)
{
    const float* head = (const float*)d_in[0];
    const float* dep  = (const float*)d_in[1];
    const float* U    = (const float*)d_in[2];
    float* out        = (float*)d_out;

    const size_t nelem = (size_t)8 * 512 * 512;
    const size_t need  = nelem * 2 * 2;   // hp+dp bf16: 8MB
    if (ws_size >= need) {
        short* hp = (short*)d_ws;
        short* dp = hp + nelem;
        pack_kernel<<<dim3(2048), dim3(256), 0, stream>>>(head, dep, hp, dp);
        bla_gemm11<<<dim3(2048), dim3(256), 0, stream>>>(hp, dp, U, out);
    } else {
        bla_fb<<<dim3(4096), dim3(256), 0, stream>>>(head, dep, U, out);
    }
}